// Round 2
// baseline (2124.184 us; speedup 1.0000x reference)
//
#include <hip/hip_runtime.h>
#include <math.h>

#define NB   256
#define NN   1024
#define ND   64
#define NSL  8
#define NHID 128
#define N_SINK 8
#define N_MESH 4
#define F_LR  3.0f
#define F_EPS 1e-8f

// ---------------------------------------------------------------- k_init
__global__ __launch_bounds__(256) void k_init_slots(
    const float* __restrict__ noise, const float* __restrict__ mu,
    const float* __restrict__ sigma, float* __restrict__ slots) {
  int i = blockIdx.x * 256 + threadIdx.x;          // 131072 total
  int d = i & 63;
  slots[i] = mu[d] + (fabsf(sigma[d]) + F_EPS) * noise[i];
}

// ---------------------------------------------------------------- k_pre
// x = LN(inputs)*g+b ; kk = |x@Wk^T|^2 ; wilog = x . wi_w + wi_b
__global__ __launch_bounds__(256) void k_pre(
    const float* __restrict__ inp, const float* __restrict__ Wk,
    const float* __restrict__ lng, const float* __restrict__ lnb,
    const float* __restrict__ wiw, const float* __restrict__ wib,
    float* __restrict__ xout, float* __restrict__ kkout, float* __restrict__ wilog) {
  __shared__ __align__(16) float xs[4][64];
  int wv = threadIdx.x >> 6, ln = threadIdx.x & 63;
  size_t row = (size_t)blockIdx.x * 4 + wv;        // < 262144
  float xi = inp[row * 64 + ln];
  float s1 = xi, s2 = xi * xi;
  #pragma unroll
  for (int m = 32; m >= 1; m >>= 1) { s1 += __shfl_xor(s1, m, 64); s2 += __shfl_xor(s2, m, 64); }
  float mean = s1 * (1.f / 64.f);
  float var  = s2 * (1.f / 64.f) - mean * mean;
  float xn = (xi - mean) * rsqrtf(var + 1e-5f) * lng[ln] + lnb[ln];
  xs[wv][ln] = xn;
  xout[row * 64 + ln] = xn;
  float wl = xn * wiw[ln];
  #pragma unroll
  for (int m = 32; m >= 1; m >>= 1) wl += __shfl_xor(wl, m, 64);
  __syncthreads();
  const float4* w4 = (const float4*)(Wk + ln * 64);
  const float4* x4 = (const float4*)xs[wv];
  float ko = 0.f;
  #pragma unroll
  for (int c = 0; c < 16; ++c) {
    float4 a = w4[c], xv = x4[c];
    ko += a.x * xv.x + a.y * xv.y + a.z * xv.z + a.w * xv.w;
  }
  float kk = ko * ko;
  #pragma unroll
  for (int m = 32; m >= 1; m >>= 1) kk += __shfl_xor(kk, m, 64);
  if (ln == 0) { kkout[row] = kk; wilog[row] = wl + wib[0]; }
}

// ---------------------------------------------------------------- k_loga
// log_a = log(8*softmax(wilog over n) + eps)
__global__ __launch_bounds__(1024) void k_loga(
    const float* __restrict__ wilog, float* __restrict__ loga) {
  __shared__ float red[16];
  __shared__ float bc;
  int b = blockIdx.x, tid = threadIdx.x;
  float x = wilog[(size_t)b * NN + tid];
  float m = x;
  #pragma unroll
  for (int s = 32; s >= 1; s >>= 1) m = fmaxf(m, __shfl_xor(m, s, 64));
  if ((tid & 63) == 0) red[tid >> 6] = m;
  __syncthreads();
  if (tid == 0) { float a = red[0]; for (int w = 1; w < 16; ++w) a = fmaxf(a, red[w]); bc = a; }
  __syncthreads();
  m = bc;
  float e = expf(x - m), se = e;
  #pragma unroll
  for (int s = 32; s >= 1; s >>= 1) se += __shfl_xor(se, s, 64);
  __syncthreads();
  if ((tid & 63) == 0) red[tid >> 6] = se;
  __syncthreads();
  if (tid == 0) { float a = 0.f; for (int w = 0; w < 16; ++w) a += red[w]; bc = a; }
  __syncthreads();
  float a8 = 8.f * e / bc;
  loga[(size_t)b * NN + tid] = logf(a8 + F_EPS);
}

// ---------------------------------------------------------------- k_slotpre
// per slot: s_n = LN(slots); q = s_n@Wq^T; qt = Wk^T q; q2=|q|^2; log_b
__global__ __launch_bounds__(512) void k_slotpre(
    const float* __restrict__ slots, const float* __restrict__ Wq,
    const float* __restrict__ Wk,
    const float* __restrict__ lng, const float* __restrict__ lnb,
    const float* __restrict__ wsw, const float* __restrict__ wsb,
    float* __restrict__ qtout, float* __restrict__ q2out, float* __restrict__ logb) {
  __shared__ __align__(16) float sn[8][64];
  __shared__ __align__(16) float qsh[8][64];
  __shared__ float bmv[8];
  int b = blockIdx.x, wv = threadIdx.x >> 6, ln = threadIdx.x & 63;
  float x = slots[((size_t)b * 8 + wv) * 64 + ln];
  float s1 = x, s2 = x * x;
  #pragma unroll
  for (int m = 32; m >= 1; m >>= 1) { s1 += __shfl_xor(s1, m, 64); s2 += __shfl_xor(s2, m, 64); }
  float mean = s1 * (1.f / 64.f);
  float var  = s2 * (1.f / 64.f) - mean * mean;
  float xn = (x - mean) * rsqrtf(var + 1e-5f) * lng[ln] + lnb[ln];
  sn[wv][ln] = xn;
  float wl = xn * wsw[ln];
  #pragma unroll
  for (int m = 32; m >= 1; m >>= 1) wl += __shfl_xor(wl, m, 64);
  if (ln == 0) bmv[wv] = wl + wsb[0];
  __syncthreads();
  float q = 0.f;
  {
    const float4* w4 = (const float4*)(Wq + ln * 64);
    const float4* x4 = (const float4*)sn[wv];
    #pragma unroll
    for (int c = 0; c < 16; ++c) {
      float4 a = w4[c], xv = x4[c];
      q += a.x * xv.x + a.y * xv.y + a.z * xv.z + a.w * xv.w;
    }
  }
  qsh[wv][ln] = q;
  float q2 = q * q;
  #pragma unroll
  for (int m = 32; m >= 1; m >>= 1) q2 += __shfl_xor(q2, m, 64);
  __syncthreads();
  // qt[e] = sum_o q[o] * Wk[o,e]
  float qt = 0.f;
  for (int o = 0; o < 64; ++o) qt = fmaf(qsh[wv][o], Wk[o * 64 + ln], qt);
  qtout[((size_t)b * 8 + wv) * 64 + ln] = qt;
  if (ln == 0) q2out[b * 8 + wv] = q2;
  if (threadIdx.x < 8) {
    float mx = bmv[0];
    #pragma unroll
    for (int j = 1; j < 8; ++j) mx = fmaxf(mx, bmv[j]);
    float ss = 0.f;
    #pragma unroll
    for (int j = 0; j < 8; ++j) ss += expf(bmv[j] - mx);
    float a8 = 8.f * expf(bmv[threadIdx.x] - mx) / ss;
    logb[b * 8 + threadIdx.x] = logf(a8 + F_EPS);
  }
}

// ---------------------------------------------------------------- k_mesh
// per batch: C from x,qt ; 4x(sinkhorn fwd + entropy-grad bwd + C update);
// final warm-started sinkhorn; write attn^T
// block reduction of an 8-vector; after return all threads hold the reduced
// vector. Lane 0 of each wave writes its 8 values with STATIC indices (no
// runtime-indexed register arrays -> no scratch).
template<int OP>  // 0 = max, 1 = sum
static __device__ __forceinline__ void block_red8(float* val, float* red, float* bcast, int tid) {
  #pragma unroll
  for (int m = 32; m >= 1; m >>= 1) {
    #pragma unroll
    for (int j = 0; j < 8; ++j) {
      float o = __shfl_xor(val[j], m, 64);
      val[j] = OP ? (val[j] + o) : fmaxf(val[j], o);
    }
  }
  int wv = tid >> 6, ln = tid & 63;
  if (ln == 0) {
    #pragma unroll
    for (int j = 0; j < 8; ++j) red[wv * 8 + j] = val[j];
  }
  __syncthreads();
  if (tid < 8) {
    float a = red[tid];
    #pragma unroll
    for (int w = 1; w < 16; ++w) { float o = red[w * 8 + tid]; a = OP ? (a + o) : fmaxf(a, o); }
    bcast[tid] = a;
  }
  __syncthreads();
  #pragma unroll
  for (int j = 0; j < 8; ++j) val[j] = bcast[j];
}

__global__ __launch_bounds__(1024) void k_mesh(
    const float* __restrict__ xg, const float* __restrict__ kkg,
    const float* __restrict__ qtg, const float* __restrict__ q2g,
    const float* __restrict__ loga, const float* __restrict__ logbg,
    float* __restrict__ attn_out) {
  __shared__ __align__(16) float qs[8][64];
  __shared__ float q2s[8];
  __shared__ float lbs[8];
  __shared__ float vhist[N_SINK][8];
  __shared__ float uhist[N_SINK][NN];
  __shared__ float red[128];
  __shared__ float bcast[8];
  int b = blockIdx.x, tid = threadIdx.x;
  if (tid < 512) ((float*)qs)[tid] = qtg[(size_t)b * 512 + tid];
  if (tid < 8) { q2s[tid] = q2g[b * 8 + tid]; lbs[tid] = logbg[b * 8 + tid]; }
  __syncthreads();

  // ---- C row (K = -C) ----
  float Know[8];
  {
    float dot[8];
    #pragma unroll
    for (int j = 0; j < 8; ++j) dot[j] = 0.f;
    const float4* xr = (const float4*)(xg + ((size_t)b * NN + tid) * ND);
    #pragma unroll 4
    for (int c = 0; c < 16; ++c) {
      float4 xv = xr[c];
      #pragma unroll
      for (int j = 0; j < 8; ++j) {
        const float4 qv = *(const float4*)&qs[j][c * 4];
        dot[j] += xv.x * qv.x + xv.y * qv.y + xv.z * qv.z + xv.w * qv.w;
      }
    }
    float kk = kkg[(size_t)b * NN + tid];
    #pragma unroll
    for (int j = 0; j < 8; ++j) {
      float d2 = kk + q2s[j] - 2.f * dot[j];
      Know[j] = -sqrtf(fmaxf(d2, 1e-12f));
    }
  }
  float la = loga[(size_t)b * NN + tid];
  float lb[8];
  #pragma unroll
  for (int j = 0; j < 8; ++j) lb[j] = lbs[j];

  float v[8], u = 0.f;
  for (int phase = 0; phase < N_MESH + 1; ++phase) {
    if (phase < N_MESH) {
      #pragma unroll
      for (int j = 0; j < 8; ++j) v[j] = 0.f;
    }
    // ---- sinkhorn forward (8 iters), storing u/v history ----
    for (int t = 0; t < N_SINK; ++t) {
      // u-step (row LSE, thread-local over the 8 slots)
      float val[8], mx = -3.4e38f;
      #pragma unroll
      for (int j = 0; j < 8; ++j) { val[j] = Know[j] + v[j]; mx = fmaxf(mx, val[j]); }
      float se = 0.f;
      #pragma unroll
      for (int j = 0; j < 8; ++j) se += expf(val[j] - mx);
      u = la - (mx + logf(se));
      uhist[t][tid] = u;
      // v-step (col LSE over n=1024, block reduce)
      float cv[8], rv[8];
      #pragma unroll
      for (int j = 0; j < 8; ++j) { cv[j] = Know[j] + u; rv[j] = cv[j]; }
      block_red8<0>(rv, red, bcast, tid);
      float sv[8];
      #pragma unroll
      for (int j = 0; j < 8; ++j) sv[j] = expf(cv[j] - rv[j]);
      block_red8<1>(sv, red, bcast, tid);
      #pragma unroll
      for (int j = 0; j < 8; ++j) v[j] = lb[j] - (rv[j] + logf(sv[j]));
      if (tid == 0) {
        #pragma unroll
        for (int j = 0; j < 8; ++j) vhist[t][j] = v[j];
      }
    }
    if (phase == N_MESH) break;   // final warm-started sinkhorn done

    // ---- backward: dH/dK with H = -sum P log(P+eps) ----
    float Kbar[8], vbar[8], ubarT;
    {
      float cs[8], gsum = 0.f;
      #pragma unroll
      for (int j = 0; j < 8; ++j) {
        float P  = expf(Know[j] + u + v[j]);
        float pe = P + F_EPS;
        float G  = -(logf(pe) + P / pe);
        float gp = G * P;
        Kbar[j] = gp; cs[j] = gp; gsum += gp;
      }
      ubarT = gsum;
      block_red8<1>(cs, red, bcast, tid);
      #pragma unroll
      for (int j = 0; j < 8; ++j) vbar[j] = cs[j];
    }
    __syncthreads();  // vhist writes visible before backward reads
    for (int t = N_SINK - 1; t >= 0; --t) {
      float ut = uhist[t][tid];
      float dsum = (t == N_SINK - 1) ? ubarT : 0.f;
      #pragma unroll
      for (int j = 0; j < 8; ++j) {
        float w  = expf(Know[j] + ut + vhist[t][j] - lb[j]);  // col-softmax entry
        float vw = vbar[j] * w;
        Kbar[j] -= vw; dsum -= vw;
      }
      float zs[8];
      #pragma unroll
      for (int j = 0; j < 8; ++j) {
        float vprev = (t > 0) ? vhist[t - 1][j] : 0.f;
        float z  = expf(Know[j] + vprev + ut - la);           // row-softmax entry
        float uz = dsum * z;
        Kbar[j] -= uz; zs[j] = uz;
      }
      if (t > 0) {
        block_red8<1>(zs, red, bcast, tid);
        #pragma unroll
        for (int j = 0; j < 8; ++j) vbar[j] = -zs[j];
      }
    }
    // C <- C - lr * dH/dC  ==>  K <- K - lr * Kbar
    #pragma unroll
    for (int j = 0; j < 8; ++j) Know[j] -= F_LR * Kbar[j];
  }
  // ---- P = exp(K+u+v); write transposed attn [b, j, i] ----
  #pragma unroll
  for (int j = 0; j < 8; ++j) {
    float P = expf(Know[j] + u + v[j]);
    attn_out[((size_t)b * 8 + j) * NN + tid] = P;
  }
}

// ---------------------------------------------------------------- k_upd
// ux = attn @ x (x read once, per-wave i-chunks) ; updates = ux @ Wv^T ;
// slot_pos = attn @ grid
__global__ __launch_bounds__(512) void k_upd(
    const float* __restrict__ attn, const float* __restrict__ xg,
    const float* __restrict__ Wv, float* __restrict__ upd,
    float* __restrict__ pos_out) {
  __shared__ __align__(16) float as[8][1024];     // 32 KB attn tile
  __shared__ __align__(16) float part[8][8][64];  // 16 KB [wave][j][e]
  int b = blockIdx.x, t = threadIdx.x;
  int wv = t >> 6, e = t & 63;
  // stage attn
  {
    const float4* src = (const float4*)(attn + (size_t)b * 8 * NN);
    float4* dst = (float4*)as;
    #pragma unroll
    for (int r = 0; r < 4; ++r) dst[t + r * 512] = src[t + r * 512];
  }
  __syncthreads();
  // wave wv owns x rows [wv*128, wv*128+128)
  float acc[8];
  #pragma unroll
  for (int j = 0; j < 8; ++j) acc[j] = 0.f;
  const float* xr = xg + ((size_t)b * NN + wv * 128) * ND + e;
  #pragma unroll 2
  for (int i4 = 0; i4 < 32; ++i4) {
    int ib = i4 * 4;
    float x0 = xr[(size_t)(ib + 0) * 64];
    float x1 = xr[(size_t)(ib + 1) * 64];
    float x2 = xr[(size_t)(ib + 2) * 64];
    float x3 = xr[(size_t)(ib + 3) * 64];
    int irow = wv * 128 + ib;
    #pragma unroll
    for (int j = 0; j < 8; ++j) {
      float4 a = *(const float4*)&as[j][irow];
      acc[j] += a.x * x0 + a.y * x1 + a.z * x2 + a.w * x3;
    }
  }
  #pragma unroll
  for (int j = 0; j < 8; ++j) part[wv][j][e] = acc[j];
  // slot_pos: wave wv handles slot j=wv
  float px = 0.f, py = 0.f;
  #pragma unroll
  for (int k = 0; k < 16; ++k) {
    int i = e + k * 64;
    float a = as[wv][i];
    px += a * (float)(i & 31);
    py += a * (float)(i >> 5);
  }
  #pragma unroll
  for (int m = 32; m >= 1; m >>= 1) { px += __shfl_xor(px, m, 64); py += __shfl_xor(py, m, 64); }
  if (e == 0) {
    pos_out[(b * 8 + wv) * 2 + 0] = px * (1.f / 31.f);
    pos_out[(b * 8 + wv) * 2 + 1] = py * (1.f / 31.f);
  }
  __syncthreads();
  // combine partials: wave wv reduces slot j=wv
  float s = 0.f;
  #pragma unroll
  for (int w = 0; w < 8; ++w) s += part[w][wv][e];
  part[0][wv][e] = s;   // reuse as ux[wv][e] (same wave reads it below)
  // updates = ux @ Wv^T
  const float4* w4 = (const float4*)(Wv + e * 64);
  const float4* u4 = (const float4*)&part[0][wv][0];
  float o = 0.f;
  #pragma unroll
  for (int c = 0; c < 16; ++c) {
    float4 uv = u4[c], wvv = w4[c];
    o += uv.x * wvv.x + uv.y * wvv.y + uv.z * wvv.z + uv.w * wvv.w;
  }
  upd[(b * 8 + wv) * 64 + e] = o;
}

// ---------------------------------------------------------------- k_gru_ff
__global__ __launch_bounds__(256) void k_gru_ff(
    const float* __restrict__ upd, float* __restrict__ slots,
    const float* __restrict__ wih, const float* __restrict__ whh,
    const float* __restrict__ bih, const float* __restrict__ bhh,
    const float* __restrict__ fc1w, const float* __restrict__ fc1b,
    const float* __restrict__ fc2w, const float* __restrict__ fc2b,
    const float* __restrict__ lng, const float* __restrict__ lnb,
    float* __restrict__ slots_out) {
  __shared__ __align__(16) float xs[4][64], hs[4][64], ys[4][64], rs[4][128];
  int wv = threadIdx.x >> 6, ln = threadIdx.x & 63;
  size_t row = (size_t)blockIdx.x * 4 + wv;   // < 2048
  float x = upd[row * 64 + ln];
  float h = slots[row * 64 + ln];
  xs[wv][ln] = x; hs[wv][ln] = h;
  __syncthreads();
  float gi0 = bih[ln], gi1 = bih[64 + ln], gi2 = bih[128 + ln];
  float gh0 = bhh[ln], gh1 = bhh[64 + ln], gh2 = bhh[128 + ln];
  {
    const float4* x4 = (const float4*)xs[wv];
    const float4* h4 = (const float4*)hs[wv];
    const float4* wi0 = (const float4*)(wih + (size_t)ln * 64);
    const float4* wi1 = (const float4*)(wih + (size_t)(64 + ln) * 64);
    const float4* wi2 = (const float4*)(wih + (size_t)(128 + ln) * 64);
    const float4* wh0 = (const float4*)(whh + (size_t)ln * 64);
    const float4* wh1 = (const float4*)(whh + (size_t)(64 + ln) * 64);
    const float4* wh2 = (const float4*)(whh + (size_t)(128 + ln) * 64);
    #pragma unroll 4
    for (int c = 0; c < 16; ++c) {
      float4 xv = x4[c], hv = h4[c], a;
      a = wi0[c]; gi0 += xv.x * a.x + xv.y * a.y + xv.z * a.z + xv.w * a.w;
      a = wi1[c]; gi1 += xv.x * a.x + xv.y * a.y + xv.z * a.z + xv.w * a.w;
      a = wi2[c]; gi2 += xv.x * a.x + xv.y * a.y + xv.z * a.z + xv.w * a.w;
      a = wh0[c]; gh0 += hv.x * a.x + hv.y * a.y + hv.z * a.z + hv.w * a.w;
      a = wh1[c]; gh1 += hv.x * a.x + hv.y * a.y + hv.z * a.z + hv.w * a.w;
      a = wh2[c]; gh2 += hv.x * a.x + hv.y * a.y + hv.z * a.z + hv.w * a.w;
    }
  }
  float r = 1.f / (1.f + expf(-(gi0 + gh0)));
  float z = 1.f / (1.f + expf(-(gi1 + gh1)));
  float n = tanhf(gi2 + r * gh2);
  float hn = (1.f - z) * n + z * h;
  // FF with pre-LN residual
  float s1 = hn, s2 = hn * hn;
  #pragma unroll
  for (int m = 32; m >= 1; m >>= 1) { s1 += __shfl_xor(s1, m, 64); s2 += __shfl_xor(s2, m, 64); }
  float mean = s1 * (1.f / 64.f);
  float var  = s2 * (1.f / 64.f) - mean * mean;
  float y = (hn - mean) * rsqrtf(var + 1e-5f) * lng[ln] + lnb[ln];
  ys[wv][ln] = y;
  __syncthreads();
  float a0 = fc1b[ln], a1 = fc1b[64 + ln];
  {
    const float4* y4 = (const float4*)ys[wv];
    const float4* f0 = (const float4*)(fc1w + (size_t)ln * 64);
    const float4* f1 = (const float4*)(fc1w + (size_t)(64 + ln) * 64);
    #pragma unroll 4
    for (int c = 0; c < 16; ++c) {
      float4 yv = y4[c], a = f0[c], bb = f1[c];
      a0 += yv.x * a.x + yv.y * a.y + yv.z * a.z + yv.w * a.w;
      a1 += yv.x * bb.x + yv.y * bb.y + yv.z * bb.z + yv.w * bb.w;
    }
  }
  rs[wv][ln] = fmaxf(a0, 0.f);
  rs[wv][64 + ln] = fmaxf(a1, 0.f);
  __syncthreads();
  float o = fc2b[ln];
  {
    const float4* r4 = (const float4*)rs[wv];
    const float4* f2 = (const float4*)(fc2w + (size_t)ln * 128);
    #pragma unroll 4
    for (int c = 0; c < 32; ++c) {
      float4 rv = r4[c], a = f2[c];
      o += rv.x * a.x + rv.y * a.y + rv.z * a.z + rv.w * a.w;
    }
  }
  float outv = hn + o;
  slots[row * 64 + ln] = outv;
  slots_out[row * 64 + ln] = outv;
}

// ---------------------------------------------------------------- launch
extern "C" void kernel_launch(void* const* d_in, const int* in_sizes, int n_in,
                              void* d_out, int out_size, void* d_ws, size_t ws_size,
                              hipStream_t stream) {
  const float* inputs = (const float*)d_in[0];
  const float* noise  = (const float*)d_in[1];
  const float* mu     = (const float*)d_in[2];
  const float* sigma  = (const float*)d_in[3];
  const float* Wq     = (const float*)d_in[4];
  const float* Wk     = (const float*)d_in[5];
  const float* Wv     = (const float*)d_in[6];
  const float* gwih   = (const float*)d_in[7];
  const float* gwhh   = (const float*)d_in[8];
  const float* gbih   = (const float*)d_in[9];
  const float* gbhh   = (const float*)d_in[10];
  const float* fc1w   = (const float*)d_in[11];
  const float* fc1b   = (const float*)d_in[12];
  const float* fc2w   = (const float*)d_in[13];
  const float* fc2b   = (const float*)d_in[14];
  const float* lnin_g = (const float*)d_in[15];
  const float* lnin_b = (const float*)d_in[16];
  const float* lns_g  = (const float*)d_in[17];
  const float* lns_b  = (const float*)d_in[18];
  const float* lnf_g  = (const float*)d_in[19];
  const float* lnf_b  = (const float*)d_in[20];
  const float* wi_w   = (const float*)d_in[21];
  const float* wi_b   = (const float*)d_in[22];
  const float* ws_w   = (const float*)d_in[23];
  const float* ws_b   = (const float*)d_in[24];

  float* out       = (float*)d_out;
  float* out_slots = out;                       // 256*8*64
  float* out_pos   = out + NB * NSL * ND;       // 256*8*2
  float* out_attn  = out_pos + NB * NSL * 2;    // 256*8*1024

  float* p = (float*)d_ws;
  float* xbuf  = p; p += (size_t)NB * NN * ND;  // 16.78M floats
  float* kkbuf = p; p += (size_t)NB * NN;
  float* wilog = p; p += (size_t)NB * NN;
  float* loga  = p; p += (size_t)NB * NN;
  float* slots = p; p += (size_t)NB * NSL * ND;
  float* qtbuf = p; p += (size_t)NB * NSL * ND;
  float* q2buf = p; p += (size_t)NB * NSL;
  float* logb  = p; p += (size_t)NB * NSL;
  float* upd   = p; p += (size_t)NB * NSL * ND;

  k_init_slots<<<(NB * NSL * ND) / 256, 256, 0, stream>>>(noise, mu, sigma, slots);
  k_pre<<<(NB * NN) / 4, 256, 0, stream>>>(inputs, Wk, lnin_g, lnin_b, wi_w, wi_b,
                                           xbuf, kkbuf, wilog);
  k_loga<<<NB, 1024, 0, stream>>>(wilog, loga);

  for (int it = 0; it < 3; ++it) {
    k_slotpre<<<NB, 512, 0, stream>>>(slots, Wq, Wk, lns_g, lns_b, ws_w, ws_b,
                                      qtbuf, q2buf, logb);
    k_mesh<<<NB, 1024, 0, stream>>>(xbuf, kkbuf, qtbuf, q2buf, loga, logb, out_attn);
    k_upd<<<NB, 512, 0, stream>>>(out_attn, xbuf, Wv, upd, out_pos);
    k_gru_ff<<<(NB * NSL) / 4, 256, 0, stream>>>(upd, slots, gwih, gwhh, gbih, gbhh,
                                                 fc1w, fc1b, fc2w, fc2b, lnf_g, lnf_b,
                                                 out_slots);
  }
}